// Round 12
// baseline (119.731 us; speedup 1.0000x reference)
//
#include <hip/hip_runtime.h>
#include <math.h>

#define N_NODES 50000
#define D_IN    128
#define E_EDGES 800000
#define H_HEADS 8
#define F_FEAT  32
#define T_TYPES 8
#define HF      256
#define NEG_SLOPE 0.2f
#define HIST_BLOCKS 64
#define GEMM_BLOCKS 391          // NGROUPS = 782 = 2*391: every block does 2 groups
#define OFF_BLOCKS  196          // ceil(50001/256)
#define K1_HIST_BASE GEMM_BLOCKS
#define K1_OFF_BASE  (GEMM_BLOCKS + HIST_BLOCKS)
#define K1_TAB       (GEMM_BLOCKS + HIST_BLOCKS + OFF_BLOCKS)
#define K1_GRID      (K1_TAB + 1)
#define NGROUPS      ((N_NODES + 63) / 64)

using short8 = __attribute__((__ext_vector_type__(8))) short;
using f32x4  = __attribute__((__ext_vector_type__(4))) float;

__device__ inline float bf2f(unsigned short u) {
    union { unsigned int i; float f; } v; v.i = ((unsigned int)u) << 16; return v.f;
}
__device__ inline unsigned short f2bf(float f) {
    unsigned int x = __float_as_uint(f);
    unsigned int r = (x + 0x7fffu + ((x >> 16) & 1u)) >> 16;
    return (unsigned short)r;
}
__device__ inline unsigned int pk2bf(float a, float b) {
    return (unsigned int)f2bf(a) | ((unsigned int)f2bf(b) << 16);
}
__device__ inline short8 cvt8(float4 a, float4 b) {
    union { unsigned int u[4]; short8 s; } ua;
    ua.u[0] = pk2bf(a.x, a.y); ua.u[1] = pk2bf(a.z, a.w);
    ua.u[2] = pk2bf(b.x, b.y); ua.u[3] = pk2bf(b.z, b.w);
    return ua.s;
}

#define MM(AF, BF, C) __builtin_amdgcn_mfma_f32_16x16x32_bf16((AF), (BF), (C), 0, 0, 0)

// ---------------------------------------------------------------------------
// Kernel 1 (fused, 4 roles): [0,391) MFMA node transform (2 groups each,
// A-prefetched, B-frag shared, 8-deep named ds_read batches);
// [391,455) histogram partials; [455,651) CSR offsets; block 651: M/ttab.
// ---------------------------------------------------------------------------
__global__ __launch_bounds__(256) void prep_kernel(const float* __restrict__ feat,
                                                   const float* __restrict__ W,
                                                   const float* __restrict__ attn_l,
                                                   const float* __restrict__ attn_r,
                                                   const int*   __restrict__ etype,
                                                   const int*   __restrict__ dst,
                                                   const float* __restrict__ attn_e,
                                                   const float* __restrict__ W_e,
                                                   const float* __restrict__ attn_et,
                                                   const float* __restrict__ W_et,
                                                   const float* __restrict__ type_emb,
                                                   unsigned short* __restrict__ fsb,
                                                   float* __restrict__ el,
                                                   float* __restrict__ er,
                                                   int* __restrict__ partials,
                                                   int* __restrict__ off,
                                                   float* __restrict__ M,
                                                   float* __restrict__ ttab) {
    __shared__ unsigned short Wl[HF * D_IN];   // 64 KB bf16, swizzled
    __shared__ int sw[4][8];
    __shared__ float q[8][32];
    const int t = threadIdx.x;

    if (blockIdx.x == K1_TAB) {                // ---- tables part (M, ttab) ----
        {
            int h = t >> 5, f2 = t & 31;
            float s = 0.f;
#pragma unroll 8
            for (int f = 0; f < F_FEAT; ++f)
                s += attn_et[h * 32 + f] * W_et[(h * 32 + f) * 32 + f2];
            q[h][f2] = s;
        }
        __syncthreads();
        if (t < 64) {
            int h = t >> 3, j = t & 7;
            float m = 0.f;
#pragma unroll 8
            for (int f = 0; f < F_FEAT; ++f)
                m += attn_e[h * 32 + f] * W_e[(h * 32 + f) * 8 + j];
            M[h * 8 + j] = m;
            float tt = 0.f;
#pragma unroll 8
            for (int f2 = 0; f2 < F_FEAT; ++f2)
                tt += type_emb[j * 32 + f2] * q[h][f2];
            ttab[j * 8 + h] = tt;   // [type][head]
        }
        return;
    }
    if (blockIdx.x >= K1_OFF_BASE) {           // ---- CSR offsets part ----
        int n = (blockIdx.x - K1_OFF_BASE) * 256 + t;
        if (n > N_NODES) return;
        int lo = 0, hi = E_EDGES;
        while (lo < hi) {
            int mid = (lo + hi) >> 1;
            if (dst[mid] < n) lo = mid + 1; else hi = mid;
        }
        off[n] = lo;
        return;
    }
    if (blockIdx.x >= K1_HIST_BASE) {          // ---- histogram part ----
        const int hb = blockIdx.x - K1_HIST_BASE;
        int c[8] = {0,0,0,0,0,0,0,0};
        const int stride = HIST_BLOCKS * 256;
        for (int e = hb * 256 + t; e < E_EDGES; e += stride) {
            int ty = etype[e];
#pragma unroll
            for (int k = 0; k < 8; ++k) c[k] += (ty == k) ? 1 : 0;
        }
#pragma unroll
        for (int k = 0; k < 8; ++k) {
            c[k] += __shfl_xor(c[k], 1);  c[k] += __shfl_xor(c[k], 2);
            c[k] += __shfl_xor(c[k], 4);  c[k] += __shfl_xor(c[k], 8);
            c[k] += __shfl_xor(c[k], 16); c[k] += __shfl_xor(c[k], 32);
        }
        const int wv = t >> 6, l = t & 63;
        if (l == 0) {
#pragma unroll
            for (int k = 0; k < 8; ++k) sw[wv][k] = c[k];
        }
        __syncthreads();
        if (t < 8) partials[hb * 8 + t] = sw[0][t] + sw[1][t] + sw[2][t] + sw[3][t];
        return;
    }

    // ---- MFMA node-transform role ----
    const int wid = t >> 6, l = t & 63;
    const int r16 = l & 15, kq = l >> 4;
    const int swz = (r16 & 7) << 3;
    const int nodeA = blockIdx.x * 64 + wid * 16;
    const int nodeB = (blockIdx.x + GEMM_BLOCKS) * 64 + wid * 16;
    int arowA = nodeA + r16; if (arowA >= N_NODES) arowA = N_NODES - 1;
    int arowB = nodeB + r16; if (arowB >= N_NODES) arowB = N_NODES - 1;
    const float* fpA = feat + (size_t)arowA * D_IN + kq * 8;
    const float* fpB = feat + (size_t)arowB * D_IN + kq * 8;
    // issue ALL 16 A-loads up front; they fly during W staging
    const float4 A0a = *(const float4*)(fpA +   0), A0b = *(const float4*)(fpA +   4);
    const float4 A1a = *(const float4*)(fpA +  32), A1b = *(const float4*)(fpA +  36);
    const float4 A2a = *(const float4*)(fpA +  64), A2b = *(const float4*)(fpA +  68);
    const float4 A3a = *(const float4*)(fpA +  96), A3b = *(const float4*)(fpA + 100);
    const float4 B0a = *(const float4*)(fpB +   0), B0b = *(const float4*)(fpB +   4);
    const float4 B1a = *(const float4*)(fpB +  32), B1b = *(const float4*)(fpB +  36);
    const float4 B2a = *(const float4*)(fpB +  64), B2b = *(const float4*)(fpB +  68);
    const float4 B3a = *(const float4*)(fpB +  96), B3b = *(const float4*)(fpB + 100);

    // stage W -> bf16 LDS (swizzled)
    for (int i = 0; i < 16; ++i) {
        int slot = i * 256 + t;
        int n = slot >> 4, k16 = slot & 15;
        const float* wp = W + (size_t)n * D_IN + k16 * 8;
        float4 w0 = *(const float4*)wp;
        float4 w1 = *(const float4*)(wp + 4);
        int idx = n * D_IN + ((k16 * 8) ^ ((n & 7) << 3));
        *(short8*)&Wl[idx] = cvt8(w0, w1);
    }
    __syncthreads();

    const short8 afA0 = cvt8(A0a, A0b), afA1 = cvt8(A1a, A1b);
    const short8 afA2 = cvt8(A2a, A2b), afA3 = cvt8(A3a, A3b);
    const short8 afB0 = cvt8(B0a, B0b), afB1 = cvt8(B1a, B1b);
    const short8 afB2 = cvt8(B2a, B2b), afB3 = cvt8(B3a, B3b);

    f32x4 accA[16], accB[16];
#pragma unroll
    for (int i = 0; i < 16; ++i) {
        accA[i] = (f32x4){0.f, 0.f, 0.f, 0.f};
        accB[i] = (f32x4){0.f, 0.f, 0.f, 0.f};
    }

#define LDB(NS, KO) (*(const short8*)&Wl[((NS) * 16 + r16) * D_IN + ((KO) ^ swz)])
#define KCBODY(KC, AFA, AFB) { \
    const int KO = (KC) * 32 + kq * 8; \
    short8 b0 = LDB(0,KO), b1 = LDB(1,KO), b2 = LDB(2,KO), b3 = LDB(3,KO); \
    short8 b4 = LDB(4,KO), b5 = LDB(5,KO), b6 = LDB(6,KO), b7 = LDB(7,KO); \
    accA[0] = MM(AFA, b0, accA[0]);  accB[0] = MM(AFB, b0, accB[0]); \
    accA[1] = MM(AFA, b1, accA[1]);  accB[1] = MM(AFB, b1, accB[1]); \
    accA[2] = MM(AFA, b2, accA[2]);  accB[2] = MM(AFB, b2, accB[2]); \
    accA[3] = MM(AFA, b3, accA[3]);  accB[3] = MM(AFB, b3, accB[3]); \
    accA[4] = MM(AFA, b4, accA[4]);  accB[4] = MM(AFB, b4, accB[4]); \
    accA[5] = MM(AFA, b5, accA[5]);  accB[5] = MM(AFB, b5, accB[5]); \
    accA[6] = MM(AFA, b6, accA[6]);  accB[6] = MM(AFB, b6, accB[6]); \
    accA[7] = MM(AFA, b7, accA[7]);  accB[7] = MM(AFB, b7, accB[7]); \
    b0 = LDB(8,KO);  b1 = LDB(9,KO);  b2 = LDB(10,KO); b3 = LDB(11,KO); \
    b4 = LDB(12,KO); b5 = LDB(13,KO); b6 = LDB(14,KO); b7 = LDB(15,KO); \
    accA[8]  = MM(AFA, b0, accA[8]);   accB[8]  = MM(AFB, b0, accB[8]); \
    accA[9]  = MM(AFA, b1, accA[9]);   accB[9]  = MM(AFB, b1, accB[9]); \
    accA[10] = MM(AFA, b2, accA[10]);  accB[10] = MM(AFB, b2, accB[10]); \
    accA[11] = MM(AFA, b3, accA[11]);  accB[11] = MM(AFB, b3, accB[11]); \
    accA[12] = MM(AFA, b4, accA[12]);  accB[12] = MM(AFB, b4, accB[12]); \
    accA[13] = MM(AFA, b5, accA[13]);  accB[13] = MM(AFB, b5, accB[13]); \
    accA[14] = MM(AFA, b6, accA[14]);  accB[14] = MM(AFB, b6, accB[14]); \
    accA[15] = MM(AFA, b7, accA[15]);  accB[15] = MM(AFB, b7, accB[15]); }

    KCBODY(0, afA0, afB0)
    KCBODY(1, afA1, afB1)
    KCBODY(2, afA2, afB2)
    KCBODY(3, afA3, afB3)

    float alv0[8], alv1[8], arv0[8], arv1[8];
#pragma unroll
    for (int h = 0; h < 8; ++h) {
        alv0[h] = attn_l[h * 32 + r16];  alv1[h] = attn_l[h * 32 + 16 + r16];
        arv0[h] = attn_r[h * 32 + r16];  arv1[h] = attn_r[h * 32 + 16 + r16];
    }

    auto epilogue = [&](f32x4* acc, int node0) {
        const int nodeb = node0 + kq * 4;
#pragma unroll
        for (int h = 0; h < 8; ++h) {
            float ev[4], rv[4];
#pragma unroll
            for (int g = 0; g < 4; ++g) {
                ev[g] = acc[2 * h][g] * alv0[h] + acc[2 * h + 1][g] * alv1[h];
                rv[g] = acc[2 * h][g] * arv0[h] + acc[2 * h + 1][g] * arv1[h];
            }
#pragma unroll
            for (int g = 0; g < 4; ++g) {
                ev[g] += __shfl_xor(ev[g], 1); ev[g] += __shfl_xor(ev[g], 2);
                ev[g] += __shfl_xor(ev[g], 4); ev[g] += __shfl_xor(ev[g], 8);
                rv[g] += __shfl_xor(rv[g], 1); rv[g] += __shfl_xor(rv[g], 2);
                rv[g] += __shfl_xor(rv[g], 4); rv[g] += __shfl_xor(rv[g], 8);
            }
            if (r16 == 0) {
#pragma unroll
                for (int g = 0; g < 4; ++g) {
                    int nd = nodeb + g;
                    if (nd < N_NODES) {
                        el[nd * 8 + h] = ev[g];
                        er[nd * 8 + h] = rv[g];
                    }
                }
            }
        }
#pragma unroll
        for (int nsub = 0; nsub < 16; ++nsub) {
            int col = nsub * 16 + r16;
#pragma unroll
            for (int g = 0; g < 4; ++g) {
                int nd = nodeb + g;
                if (nd < N_NODES) fsb[(size_t)nd * HF + col] = f2bf(acc[nsub][g]);
            }
        }
    };
    epilogue(accA, nodeA);
    epilogue(accB, nodeB);
}

// ---------------------------------------------------------------------------
// Kernel 2: per-edge p = exp(leakyrelu(w*(el+er+escore+tscore))), bf16 out.
//   w[t] reduced per-block from the 64x8 partials (2 KB, L2-broadcast).
// ---------------------------------------------------------------------------
__global__ __launch_bounds__(256) void edge_kernel(const float* __restrict__ ee,
        const int* __restrict__ src, const int* __restrict__ dst,
        const int* __restrict__ etype, const float* __restrict__ el,
        const float* __restrict__ er, const float* __restrict__ M,
        const float* __restrict__ ttab, const int* __restrict__ partials,
        unsigned short* __restrict__ pexp) {
    __shared__ float sM[64], sT[64], sw[8];
    int t = threadIdx.x;
    if (t < 64) {
        sM[t] = M[t]; sT[t] = ttab[t];
        int j = t & 7, b = t >> 3;
        int c = 0;
#pragma unroll 8
        for (int i = 0; i < HIST_BLOCKS / 8; ++i)
            c += partials[(b + 8 * i) * 8 + j];
        c += __shfl_xor(c, 8); c += __shfl_xor(c, 16); c += __shfl_xor(c, 32);
        if (t < 8) {
            if (c < 1) c = 1;
            sw[t] = (float)E_EDGES / (8.0f * (float)c);
        }
    }
    __syncthreads();
    int e = blockIdx.x * 256 + t;
    if (e >= E_EDGES) return;
    int s = src[e], d = dst[e], ty = etype[e];
    float4 e0 = *(const float4*)&ee[(size_t)e * 8];
    float4 e1 = *(const float4*)&ee[(size_t)e * 8 + 4];
    float4 l0 = *(const float4*)&el[s * 8];
    float4 l1 = *(const float4*)&el[s * 8 + 4];
    float4 r0 = *(const float4*)&er[d * 8];
    float4 r1 = *(const float4*)&er[d * 8 + 4];
    float wt = sw[ty];
    float lv[8] = {l0.x,l0.y,l0.z,l0.w,l1.x,l1.y,l1.z,l1.w};
    float rv[8] = {r0.x,r0.y,r0.z,r0.w,r1.x,r1.y,r1.z,r1.w};
    unsigned int o[4];
#pragma unroll
    for (int hp = 0; hp < 4; ++hp) {
        float p2[2];
#pragma unroll
        for (int i = 0; i < 2; ++i) {
            int h = hp * 2 + i;
            float sc = lv[h] + rv[h] + sT[ty * 8 + h];
            sc += e0.x*sM[h*8+0] + e0.y*sM[h*8+1] + e0.z*sM[h*8+2] + e0.w*sM[h*8+3]
                + e1.x*sM[h*8+4] + e1.y*sM[h*8+5] + e1.z*sM[h*8+6] + e1.w*sM[h*8+7];
            sc *= wt;
            sc = (sc >= 0.f) ? sc : NEG_SLOPE * sc;
            p2[i] = __expf(sc);
        }
        o[hp] = (unsigned int)f2bf(p2[0]) | ((unsigned int)f2bf(p2[1]) << 16);
    }
    *(uint4*)&pexp[(size_t)e * 8] = make_uint4(o[0], o[1], o[2], o[3]);
}

// ---------------------------------------------------------------------------
// Kernel 3: single-pass softmax-normalized aggregation. One wave per dst node.
// ---------------------------------------------------------------------------
__global__ __launch_bounds__(256) void agg_kernel(const unsigned short* __restrict__ pexp,
        const unsigned short* __restrict__ fsb, const int* __restrict__ src,
        const int* __restrict__ off, const float* __restrict__ bias,
        float* __restrict__ out) {
    __shared__ unsigned short plds[4][64][8];   // wave-private p scratch (4 KB)
    const int wid = threadIdx.x >> 6;
    const int l = threadIdx.x & 63;
    const int n = blockIdx.x * 4 + wid;
    if (n >= N_NODES) return;
    const int beg = off[n], end = off[n + 1];
    const int c0 = 4 * l;
    const int h = l >> 3;
    const float4 b4 = *(const float4*)&bias[c0];
    float* op = &out[(size_t)n * HF + c0];
    if (beg == end) { *(float4*)op = b4; return; }
    const unsigned short* mp = &plds[wid][0][0];
    float a0 = 0.f, a1 = 0.f, a2 = 0.f, a3 = 0.f, z = 0.f;
    for (int base = beg; base < end; base += 64) {
        const int remn = end - base;
        const int rem = remn < 64 ? remn : 64;
        int idx = base + l; if (idx >= end) idx = end - 1;
        const int sl = src[idx];                 // coalesced
        {   // stage this chunk's pexp block (64x8 bf16 = 1KB) into LDS
            const uint4 pv = *(const uint4*)&pexp[(size_t)idx * 8];
            *(uint4*)&plds[wid][l][0] = pv;
        }
        int j = 0;
        for (; j + 4 <= rem; j += 4) {
            const int s0 = __shfl(sl, j),     s1 = __shfl(sl, j + 1);
            const int s2 = __shfl(sl, j + 2), s3 = __shfl(sl, j + 3);
            const float p0 = bf2f(mp[(j    ) * 8 + h]);
            const float p1 = bf2f(mp[(j + 1) * 8 + h]);
            const float p2 = bf2f(mp[(j + 2) * 8 + h]);
            const float p3 = bf2f(mp[(j + 3) * 8 + h]);
            const ushort4 f0 = *(const ushort4*)&fsb[(size_t)s0 * HF + c0];
            const ushort4 f1 = *(const ushort4*)&fsb[(size_t)s1 * HF + c0];
            const ushort4 f2 = *(const ushort4*)&fsb[(size_t)s2 * HF + c0];
            const ushort4 f3 = *(const ushort4*)&fsb[(size_t)s3 * HF + c0];
            a0 += p0 * bf2f(f0.x); a1 += p0 * bf2f(f0.y);
            a2 += p0 * bf2f(f0.z); a3 += p0 * bf2f(f0.w); z += p0;
            a0 += p1 * bf2f(f1.x); a1 += p1 * bf2f(f1.y);
            a2 += p1 * bf2f(f1.z); a3 += p1 * bf2f(f1.w); z += p1;
            a0 += p2 * bf2f(f2.x); a1 += p2 * bf2f(f2.y);
            a2 += p2 * bf2f(f2.z); a3 += p2 * bf2f(f2.w); z += p2;
            a0 += p3 * bf2f(f3.x); a1 += p3 * bf2f(f3.y);
            a2 += p3 * bf2f(f3.z); a3 += p3 * bf2f(f3.w); z += p3;
        }
        for (; j < rem; ++j) {
            const int s0 = __shfl(sl, j);
            const float p0 = bf2f(mp[j * 8 + h]);
            const ushort4 f0 = *(const ushort4*)&fsb[(size_t)s0 * HF + c0];
            a0 += p0 * bf2f(f0.x); a1 += p0 * bf2f(f0.y);
            a2 += p0 * bf2f(f0.z); a3 += p0 * bf2f(f0.w); z += p0;
        }
    }
    const float rz = 1.f / z;
    *(float4*)op = make_float4(a0 * rz + b4.x, a1 * rz + b4.y,
                               a2 * rz + b4.z, a3 * rz + b4.w);
}

// ---------------------------------------------------------------------------
extern "C" void kernel_launch(void* const* d_in, const int* in_sizes, int n_in,
                              void* d_out, int out_size, void* d_ws, size_t ws_size,
                              hipStream_t stream) {
    const float* feat     = (const float*)d_in[0];
    const float* ee       = (const float*)d_in[1];
    const int*   src      = (const int*)d_in[2];
    const int*   dst      = (const int*)d_in[3];
    const int*   etype    = (const int*)d_in[4];
    const float* W_src    = (const float*)d_in[5];
    const float* attn_l   = (const float*)d_in[6];
    const float* attn_r   = (const float*)d_in[7];
    const float* attn_e   = (const float*)d_in[8];
    const float* W_e      = (const float*)d_in[9];
    const float* type_emb = (const float*)d_in[10];
    const float* W_et     = (const float*)d_in[11];
    const float* attn_et  = (const float*)d_in[12];
    const float* bias     = (const float*)d_in[13];
    float* out = (float*)d_out;

    char* ws = (char*)d_ws;
    size_t o = 0;
    auto alloc = [&](size_t bytes) -> void* {
        void* p = ws + o;
        o = (o + bytes + 255) & ~(size_t)255;
        return p;
    };
    unsigned short* fsb  = (unsigned short*)alloc((size_t)N_NODES * HF * 2); // 25.6 MB
    unsigned short* pexp = (unsigned short*)alloc((size_t)E_EDGES * 8 * 2);  // 12.8 MB
    float* el    = (float*)alloc((size_t)N_NODES * 8 * 4);
    float* er    = (float*)alloc((size_t)N_NODES * 8 * 4);
    int*   off   = (int*)alloc((size_t)(N_NODES + 1) * 4);
    int*   partials = (int*)alloc((size_t)HIST_BLOCKS * 8 * 4);
    float* M     = (float*)alloc(64 * 4);
    float* ttab  = (float*)alloc(64 * 4);

    prep_kernel<<<K1_GRID, 256, 0, stream>>>(feat, W_src, attn_l, attn_r,
                                             etype, dst, attn_e, W_e, attn_et,
                                             W_et, type_emb, fsb, el, er,
                                             partials, off, M, ttab);
    edge_kernel<<<(E_EDGES + 255) / 256, 256, 0, stream>>>(
        ee, src, dst, etype, el, er, M, ttab, partials, pexp);
    agg_kernel<<<(N_NODES + 3) / 4, 256, 0, stream>>>(pexp, fsb, src, off, bias, out);
}

// Round 13
// 105.697 us; speedup vs baseline: 1.1328x; 1.1328x over previous
//
#include <hip/hip_runtime.h>
#include <math.h>

#define N_NODES 50000
#define D_IN    128
#define E_EDGES 800000
#define H_HEADS 8
#define F_FEAT  32
#define T_TYPES 8
#define HF      256
#define NEG_SLOPE 0.2f
#define HIST_BLOCKS 64
#define GEMM_BLOCKS 391          // NGROUPS = 782 = 2*391, perfectly balanced
#define OFF_BLOCKS  196          // ceil(50001/256)
#define K1_HIST_BASE GEMM_BLOCKS
#define K1_OFF_BASE  (GEMM_BLOCKS + HIST_BLOCKS)
#define K1_TAB       (GEMM_BLOCKS + HIST_BLOCKS + OFF_BLOCKS)
#define K1_GRID      (K1_TAB + 1)
#define NGROUPS      ((N_NODES + 63) / 64)

using short8 = __attribute__((__ext_vector_type__(8))) short;
using f32x4  = __attribute__((__ext_vector_type__(4))) float;

__device__ inline float bf2f(unsigned short u) {
    union { unsigned int i; float f; } v; v.i = ((unsigned int)u) << 16; return v.f;
}
__device__ inline unsigned short f2bf(float f) {
    unsigned int x = __float_as_uint(f);
    unsigned int r = (x + 0x7fffu + ((x >> 16) & 1u)) >> 16;
    return (unsigned short)r;
}
__device__ inline unsigned int pk2bf(float a, float b) {
    return (unsigned int)f2bf(a) | ((unsigned int)f2bf(b) << 16);
}

// ---------------------------------------------------------------------------
// Kernel 1 (fused, 4 roles): [0,391) MFMA node transform (2 node-groups each);
// [391,455) histogram partials; [455,651) CSR offsets; block 651: M/ttab
// tables. All roles mutually independent.
// ---------------------------------------------------------------------------
__global__ __launch_bounds__(256) void prep_kernel(const float* __restrict__ feat,
                                                   const float* __restrict__ W,
                                                   const float* __restrict__ attn_l,
                                                   const float* __restrict__ attn_r,
                                                   const int*   __restrict__ etype,
                                                   const int*   __restrict__ dst,
                                                   const float* __restrict__ attn_e,
                                                   const float* __restrict__ W_e,
                                                   const float* __restrict__ attn_et,
                                                   const float* __restrict__ W_et,
                                                   const float* __restrict__ type_emb,
                                                   unsigned short* __restrict__ fsb,
                                                   float* __restrict__ el,
                                                   float* __restrict__ er,
                                                   int* __restrict__ partials,
                                                   int* __restrict__ off,
                                                   float* __restrict__ M,
                                                   float* __restrict__ ttab) {
    __shared__ unsigned short Wl[HF * D_IN];   // 64 KB bf16, swizzled
    __shared__ int sw[4][8];
    __shared__ float q[8][32];
    const int t = threadIdx.x;

    if (blockIdx.x == K1_TAB) {                // ---- tables part (M, ttab) ----
        {   // q[h][f2], thread = h*32+f2, coalesced W_et reads
            int h = t >> 5, f2 = t & 31;
            float s = 0.f;
#pragma unroll 8
            for (int f = 0; f < F_FEAT; ++f)
                s += attn_et[h * 32 + f] * W_et[(h * 32 + f) * 32 + f2];
            q[h][f2] = s;
        }
        __syncthreads();
        if (t < 64) {
            int h = t >> 3, j = t & 7;
            float m = 0.f;
#pragma unroll 8
            for (int f = 0; f < F_FEAT; ++f)
                m += attn_e[h * 32 + f] * W_e[(h * 32 + f) * 8 + j];
            M[h * 8 + j] = m;
            float tt = 0.f;
#pragma unroll 8
            for (int f2 = 0; f2 < F_FEAT; ++f2)
                tt += type_emb[j * 32 + f2] * q[h][f2];
            ttab[j * 8 + h] = tt;   // [type][head]
        }
        return;
    }
    if (blockIdx.x >= K1_OFF_BASE) {           // ---- CSR offsets part ----
        int n = (blockIdx.x - K1_OFF_BASE) * 256 + t;
        if (n > N_NODES) return;
        int lo = 0, hi = E_EDGES;
        while (lo < hi) {
            int mid = (lo + hi) >> 1;
            if (dst[mid] < n) lo = mid + 1; else hi = mid;
        }
        off[n] = lo;
        return;
    }
    if (blockIdx.x >= K1_HIST_BASE) {          // ---- histogram part ----
        const int hb = blockIdx.x - K1_HIST_BASE;
        int c[8] = {0,0,0,0,0,0,0,0};
        const int stride = HIST_BLOCKS * 256;
        for (int e = hb * 256 + t; e < E_EDGES; e += stride) {
            int ty = etype[e];
#pragma unroll
            for (int k = 0; k < 8; ++k) c[k] += (ty == k) ? 1 : 0;
        }
#pragma unroll
        for (int k = 0; k < 8; ++k) {
            c[k] += __shfl_xor(c[k], 1);  c[k] += __shfl_xor(c[k], 2);
            c[k] += __shfl_xor(c[k], 4);  c[k] += __shfl_xor(c[k], 8);
            c[k] += __shfl_xor(c[k], 16); c[k] += __shfl_xor(c[k], 32);
        }
        const int wv = t >> 6, l = t & 63;
        if (l == 0) {
#pragma unroll
            for (int k = 0; k < 8; ++k) sw[wv][k] = c[k];
        }
        __syncthreads();
        if (t < 8) partials[hb * 8 + t] = sw[0][t] + sw[1][t] + sw[2][t] + sw[3][t];
        return;
    }

    // ---- MFMA node-transform part (exactly 2 node groups per block) ----
    for (int i = 0; i < 16; ++i) {
        int slot = i * 256 + t;
        int n = slot >> 4, k16 = slot & 15;
        const float* wp = W + (size_t)n * D_IN + k16 * 8;
        float4 w0 = *(const float4*)wp;
        float4 w1 = *(const float4*)(wp + 4);
        union { unsigned int u[4]; short8 s; } ua;
        ua.u[0] = pk2bf(w0.x, w0.y); ua.u[1] = pk2bf(w0.z, w0.w);
        ua.u[2] = pk2bf(w1.x, w1.y); ua.u[3] = pk2bf(w1.z, w1.w);
        int idx = n * D_IN + ((k16 * 8) ^ ((n & 7) << 3));
        *(short8*)&Wl[idx] = ua.s;
    }
    __syncthreads();

    const int wid = t >> 6, l = t & 63;
    const int r16 = l & 15, kq = l >> 4;
    float alv0[8], alv1[8], arv0[8], arv1[8];
#pragma unroll
    for (int h = 0; h < 8; ++h) {
        alv0[h] = attn_l[h * 32 + r16];  alv1[h] = attn_l[h * 32 + 16 + r16];
        arv0[h] = attn_r[h * 32 + r16];  arv1[h] = attn_r[h * 32 + 16 + r16];
    }

    for (int grp = blockIdx.x; grp < NGROUPS; grp += GEMM_BLOCKS) {
        const int node0 = grp * 64 + wid * 16;
        int arow = node0 + r16;
        if (arow >= N_NODES) arow = N_NODES - 1;   // clamp; stores guarded
        const float* fp = feat + (size_t)arow * D_IN + kq * 8;

        f32x4 acc[16];
#pragma unroll
        for (int i = 0; i < 16; ++i) acc[i] = (f32x4){0.f, 0.f, 0.f, 0.f};

#pragma unroll
        for (int kc = 0; kc < 4; ++kc) {
            float4 a0 = *(const float4*)(fp + kc * 32);
            float4 a1 = *(const float4*)(fp + kc * 32 + 4);
            union { unsigned int u[4]; short8 s; } ua;
            ua.u[0] = pk2bf(a0.x, a0.y); ua.u[1] = pk2bf(a0.z, a0.w);
            ua.u[2] = pk2bf(a1.x, a1.y); ua.u[3] = pk2bf(a1.z, a1.w);
            short8 af = ua.s;
#pragma unroll
            for (int nsub = 0; nsub < 16; ++nsub) {
                int n = nsub * 16 + r16;
                int idx = n * D_IN + ((kc * 32 + kq * 8) ^ ((n & 7) << 3));
                short8 bf = *(short8*)&Wl[idx];
                acc[nsub] = __builtin_amdgcn_mfma_f32_16x16x32_bf16(af, bf, acc[nsub], 0, 0, 0);
            }
        }

        const int nodeb = node0 + kq * 4;
#pragma unroll
        for (int h = 0; h < 8; ++h) {
            float ev[4], rv[4];
#pragma unroll
            for (int g = 0; g < 4; ++g) {
                ev[g] = acc[2 * h][g] * alv0[h] + acc[2 * h + 1][g] * alv1[h];
                rv[g] = acc[2 * h][g] * arv0[h] + acc[2 * h + 1][g] * arv1[h];
            }
#pragma unroll
            for (int g = 0; g < 4; ++g) {
                ev[g] += __shfl_xor(ev[g], 1); ev[g] += __shfl_xor(ev[g], 2);
                ev[g] += __shfl_xor(ev[g], 4); ev[g] += __shfl_xor(ev[g], 8);
                rv[g] += __shfl_xor(rv[g], 1); rv[g] += __shfl_xor(rv[g], 2);
                rv[g] += __shfl_xor(rv[g], 4); rv[g] += __shfl_xor(rv[g], 8);
            }
            if (r16 == 0) {
#pragma unroll
                for (int g = 0; g < 4; ++g) {
                    int nd = nodeb + g;
                    if (nd < N_NODES) {
                        el[nd * 8 + h] = ev[g];
                        er[nd * 8 + h] = rv[g];
                    }
                }
            }
        }
#pragma unroll
        for (int nsub = 0; nsub < 16; ++nsub) {
            int col = nsub * 16 + r16;
#pragma unroll
            for (int g = 0; g < 4; ++g) {
                int nd = nodeb + g;
                if (nd < N_NODES) fsb[(size_t)nd * HF + col] = f2bf(acc[nsub][g]);
            }
        }
    }
}

// ---------------------------------------------------------------------------
// Kernel 2: per-edge p = exp(leakyrelu(w*(el+er+escore+tscore))), bf16 out.
//   w[t] reduced per-block from the 64x8 partials (2 KB, L2-broadcast).
// ---------------------------------------------------------------------------
__global__ __launch_bounds__(256) void edge_kernel(const float* __restrict__ ee,
        const int* __restrict__ src, const int* __restrict__ dst,
        const int* __restrict__ etype, const float* __restrict__ el,
        const float* __restrict__ er, const float* __restrict__ M,
        const float* __restrict__ ttab, const int* __restrict__ partials,
        unsigned short* __restrict__ pexp) {
    __shared__ float sM[64], sT[64], sw[8];
    int t = threadIdx.x;
    if (t < 64) {
        sM[t] = M[t]; sT[t] = ttab[t];
        // counts reduce: bin j = t&7, base block b = t>>3, stride 8
        int j = t & 7, b = t >> 3;
        int c = 0;
#pragma unroll 8
        for (int i = 0; i < HIST_BLOCKS / 8; ++i)
            c += partials[(b + 8 * i) * 8 + j];
        c += __shfl_xor(c, 8); c += __shfl_xor(c, 16); c += __shfl_xor(c, 32);
        if (t < 8) {
            if (c < 1) c = 1;
            sw[t] = (float)E_EDGES / (8.0f * (float)c);
        }
    }
    __syncthreads();
    int e = blockIdx.x * 256 + t;
    if (e >= E_EDGES) return;
    int s = src[e], d = dst[e], ty = etype[e];
    float4 e0 = *(const float4*)&ee[(size_t)e * 8];
    float4 e1 = *(const float4*)&ee[(size_t)e * 8 + 4];
    float4 l0 = *(const float4*)&el[s * 8];
    float4 l1 = *(const float4*)&el[s * 8 + 4];
    float4 r0 = *(const float4*)&er[d * 8];
    float4 r1 = *(const float4*)&er[d * 8 + 4];
    float wt = sw[ty];
    float lv[8] = {l0.x,l0.y,l0.z,l0.w,l1.x,l1.y,l1.z,l1.w};
    float rv[8] = {r0.x,r0.y,r0.z,r0.w,r1.x,r1.y,r1.z,r1.w};
    unsigned int o[4];
#pragma unroll
    for (int hp = 0; hp < 4; ++hp) {
        float p2[2];
#pragma unroll
        for (int i = 0; i < 2; ++i) {
            int h = hp * 2 + i;
            float sc = lv[h] + rv[h] + sT[ty * 8 + h];
            sc += e0.x*sM[h*8+0] + e0.y*sM[h*8+1] + e0.z*sM[h*8+2] + e0.w*sM[h*8+3]
                + e1.x*sM[h*8+4] + e1.y*sM[h*8+5] + e1.z*sM[h*8+6] + e1.w*sM[h*8+7];
            sc *= wt;
            sc = (sc >= 0.f) ? sc : NEG_SLOPE * sc;
            p2[i] = __expf(sc);
        }
        o[hp] = (unsigned int)f2bf(p2[0]) | ((unsigned int)f2bf(p2[1]) << 16);
    }
    *(uint4*)&pexp[(size_t)e * 8] = make_uint4(o[0], o[1], o[2], o[3]);
}

// ---------------------------------------------------------------------------
// Kernel 3: single-pass softmax-normalized aggregation. One wave per dst node.
//   Coalesced src read (-> shfl) + pexp chunk staged to wave-private LDS;
//   inner loop = named-scalar unroll-4, fs gather the only global load.
// ---------------------------------------------------------------------------
__global__ __launch_bounds__(256) void agg_kernel(const unsigned short* __restrict__ pexp,
        const unsigned short* __restrict__ fsb, const int* __restrict__ src,
        const int* __restrict__ off, const float* __restrict__ bias,
        float* __restrict__ out) {
    __shared__ unsigned short plds[4][64][8];   // wave-private p scratch (4 KB)
    const int wid = threadIdx.x >> 6;
    const int l = threadIdx.x & 63;
    const int n = blockIdx.x * 4 + wid;
    if (n >= N_NODES) return;
    const int beg = off[n], end = off[n + 1];
    const int c0 = 4 * l;
    const int h = l >> 3;
    const float4 b4 = *(const float4*)&bias[c0];
    float* op = &out[(size_t)n * HF + c0];
    if (beg == end) { *(float4*)op = b4; return; }
    const unsigned short* mp = &plds[wid][0][0];
    float a0 = 0.f, a1 = 0.f, a2 = 0.f, a3 = 0.f, z = 0.f;
    for (int base = beg; base < end; base += 64) {
        const int remn = end - base;
        const int rem = remn < 64 ? remn : 64;
        int idx = base + l; if (idx >= end) idx = end - 1;
        const int sl = src[idx];                 // coalesced
        {   // stage this chunk's pexp block (64x8 bf16 = 1KB) into LDS
            const uint4 pv = *(const uint4*)&pexp[(size_t)idx * 8];
            *(uint4*)&plds[wid][l][0] = pv;
        }
        int j = 0;
        for (; j + 4 <= rem; j += 4) {
            const int s0 = __shfl(sl, j),     s1 = __shfl(sl, j + 1);
            const int s2 = __shfl(sl, j + 2), s3 = __shfl(sl, j + 3);
            const float p0 = bf2f(mp[(j    ) * 8 + h]);
            const float p1 = bf2f(mp[(j + 1) * 8 + h]);
            const float p2 = bf2f(mp[(j + 2) * 8 + h]);
            const float p3 = bf2f(mp[(j + 3) * 8 + h]);
            const ushort4 f0 = *(const ushort4*)&fsb[(size_t)s0 * HF + c0];
            const ushort4 f1 = *(const ushort4*)&fsb[(size_t)s1 * HF + c0];
            const ushort4 f2 = *(const ushort4*)&fsb[(size_t)s2 * HF + c0];
            const ushort4 f3 = *(const ushort4*)&fsb[(size_t)s3 * HF + c0];
            a0 += p0 * bf2f(f0.x); a1 += p0 * bf2f(f0.y);
            a2 += p0 * bf2f(f0.z); a3 += p0 * bf2f(f0.w); z += p0;
            a0 += p1 * bf2f(f1.x); a1 += p1 * bf2f(f1.y);
            a2 += p1 * bf2f(f1.z); a3 += p1 * bf2f(f1.w); z += p1;
            a0 += p2 * bf2f(f2.x); a1 += p2 * bf2f(f2.y);
            a2 += p2 * bf2f(f2.z); a3 += p2 * bf2f(f2.w); z += p2;
            a0 += p3 * bf2f(f3.x); a1 += p3 * bf2f(f3.y);
            a2 += p3 * bf2f(f3.z); a3 += p3 * bf2f(f3.w); z += p3;
        }
        for (; j < rem; ++j) {
            const int s0 = __shfl(sl, j);
            const float p0 = bf2f(mp[j * 8 + h]);
            const ushort4 f0 = *(const ushort4*)&fsb[(size_t)s0 * HF + c0];
            a0 += p0 * bf2f(f0.x); a1 += p0 * bf2f(f0.y);
            a2 += p0 * bf2f(f0.z); a3 += p0 * bf2f(f0.w); z += p0;
        }
    }
    const float rz = 1.f / z;
    *(float4*)op = make_float4(a0 * rz + b4.x, a1 * rz + b4.y,
                               a2 * rz + b4.z, a3 * rz + b4.w);
}

// ---------------------------------------------------------------------------
extern "C" void kernel_launch(void* const* d_in, const int* in_sizes, int n_in,
                              void* d_out, int out_size, void* d_ws, size_t ws_size,
                              hipStream_t stream) {
    const float* feat     = (const float*)d_in[0];
    const float* ee       = (const float*)d_in[1];
    const int*   src      = (const int*)d_in[2];
    const int*   dst      = (const int*)d_in[3];
    const int*   etype    = (const int*)d_in[4];
    const float* W_src    = (const float*)d_in[5];
    const float* attn_l   = (const float*)d_in[6];
    const float* attn_r   = (const float*)d_in[7];
    const float* attn_e   = (const float*)d_in[8];
    const float* W_e      = (const float*)d_in[9];
    const float* type_emb = (const float*)d_in[10];
    const float* W_et     = (const float*)d_in[11];
    const float* attn_et  = (const float*)d_in[12];
    const float* bias     = (const float*)d_in[13];
    float* out = (float*)d_out;

    char* ws = (char*)d_ws;
    size_t o = 0;
    auto alloc = [&](size_t bytes) -> void* {
        void* p = ws + o;
        o = (o + bytes + 255) & ~(size_t)255;
        return p;
    };
    unsigned short* fsb  = (unsigned short*)alloc((size_t)N_NODES * HF * 2); // 25.6 MB
    unsigned short* pexp = (unsigned short*)alloc((size_t)E_EDGES * 8 * 2);  // 12.8 MB
    float* el    = (float*)alloc((size_t)N_NODES * 8 * 4);
    float* er    = (float*)alloc((size_t)N_NODES * 8 * 4);
    int*   off   = (int*)alloc((size_t)(N_NODES + 1) * 4);
    int*   partials = (int*)alloc((size_t)HIST_BLOCKS * 8 * 4);
    float* M     = (float*)alloc(64 * 4);
    float* ttab  = (float*)alloc(64 * 4);

    prep_kernel<<<K1_GRID, 256, 0, stream>>>(feat, W_src, attn_l, attn_r,
                                             etype, dst, attn_e, W_e, attn_et,
                                             W_et, type_emb, fsb, el, er,
                                             partials, off, M, ttab);
    edge_kernel<<<(E_EDGES + 255) / 256, 256, 0, stream>>>(
        ee, src, dst, etype, el, er, M, ttab, partials, pexp);
    agg_kernel<<<(N_NODES + 3) / 4, 256, 0, stream>>>(pexp, fsb, src, off, bias, out);
}